// Round 3
// baseline (268.147 us; speedup 1.0000x reference)
//
#include <hip/hip_runtime.h>
#include <math.h>

// Attn_83854941487646: out = softmax(tanh(Q) @ H^T) @ H
// B=8, Q=2048, K=2048, Hdim=128, fp32 in/out.
// R3: fused last-block combine (no 2nd launch), PV via mfma_16x16x16f16
//     (S-regs feed B-operand directly, Ps LDS round-trip eliminated),
//     splits=4 -> 4 blocks/CU.

typedef _Float16 half8 __attribute__((ext_vector_type(8)));
typedef _Float16 half4 __attribute__((ext_vector_type(4)));
typedef float    f32x4 __attribute__((ext_vector_type(4)));

#define QQ 2048
#define KK 2048
#define HH 128
#define BM 64
#define BN 64
#define NTILES 32
#define KS_STR 136           // halves: 128 + 8 pad (b128 reads land min-rounds)
#define VT_STR 72            // halves: 64 + 8 pad
#define L2E 1.44269504f
#define NGROUPS 256          // 8 batches x 32 q-blocks
#define OSPLIT  ((size_t)NGROUPS * BM * HH)   // floats per split (O partials)
#define MLSPLIT ((size_t)NGROUPS * BM)        // floats per split (each of m,l)

union U32H { unsigned int u; _Float16 h[2]; };

__launch_bounds__(256, 4)
__global__ void attn_main(const float* __restrict__ out_state,
                          const float* __restrict__ history,
                          float* __restrict__ out,
                          float* __restrict__ ws,
                          int splits) {
    __shared__ _Float16 Ks[BN * KS_STR];   // 17408 B  row-major K tile [key][h]
    __shared__ _Float16 Vt[HH * VT_STR];   // 18432 B  transposed [h][key]
    __shared__ int lastFlag;

    const int tid  = threadIdx.x;
    const int wave = tid >> 6;
    const int lane = tid & 63;
    const int quad = lane >> 4;
    const int lc   = lane & 15;

    const int bid = blockIdx.x;
    const int s   = bid >> 8;           // split id
    const int g   = bid & 255;          // group id
    const int b   = g >> 5;
    const int qb  = g & 31;
    const int m0  = qb * BM;

    const int kt0 = (NTILES * s) / splits;
    const int kt1 = (NTILES * (s + 1)) / splits;

    // Q fragment (MFMA B operand for S^T = K.Q^T): lane holds Q[m=lc][k=quad*8+j]
    half8 qf[4];
    {
        const int m = m0 + wave * 16 + lc;
        const float* qrow = out_state + ((size_t)b * QQ + m) * HH;
        #pragma unroll
        for (int s4 = 0; s4 < 4; ++s4) {
            const int h0 = 32 * s4 + quad * 8;
            const float4 a = *(const float4*)(qrow + h0);
            const float4 c = *(const float4*)(qrow + h0 + 4);
            qf[s4][0] = (_Float16)tanhf(a.x); qf[s4][1] = (_Float16)tanhf(a.y);
            qf[s4][2] = (_Float16)tanhf(a.z); qf[s4][3] = (_Float16)tanhf(a.w);
            qf[s4][4] = (_Float16)tanhf(c.x); qf[s4][5] = (_Float16)tanhf(c.y);
            qf[s4][6] = (_Float16)tanhf(c.z); qf[s4][7] = (_Float16)tanhf(c.w);
        }
    }

    const f32x4 zero4 = {0.f, 0.f, 0.f, 0.f};
    f32x4 O[8];                 // O^T tile ct: rows h=16ct+quad*4+r, col q=lc
    #pragma unroll
    for (int i = 0; i < 8; ++i) O[i] = zero4;
    f32x4 Osum = zero4;
    float rmax = -3.0e38f;

    const int r0  = tid >> 5;           // stage1 key-row base
    const int c4  = (tid & 31) * 4;     // stage1 h col (float4)
    const int h0  = 2 * (tid & 63);     // stage2 h-pair
    const int n0t = (tid >> 6) * 16;    // stage2 16-key group

    const half4 ones4 = {(_Float16)1.f, (_Float16)1.f, (_Float16)1.f, (_Float16)1.f};

    for (int kt = kt0; kt < kt1; ++kt) {
        const int n0 = kt * BN;

        // stage 0: coalesced global prefetch into regs
        float4 gbuf[8];
        const float* hb = history + ((size_t)b * KK + n0) * HH;
        #pragma unroll
        for (int j = 0; j < 8; ++j)
            gbuf[j] = *(const float4*)(hb + (size_t)(r0 + 8 * j) * HH + c4);

        __syncthreads();                 // previous tile's compute done
        // stage 1: Ks row-major f16
        #pragma unroll
        for (int j = 0; j < 8; ++j) {
            half4 hv;
            hv[0] = (_Float16)gbuf[j].x; hv[1] = (_Float16)gbuf[j].y;
            hv[2] = (_Float16)gbuf[j].z; hv[3] = (_Float16)gbuf[j].w;
            *(half4*)&Ks[(r0 + 8 * j) * KS_STR + c4] = hv;
        }
        __syncthreads();                 // Ks ready
        // stage 2: transpose Ks -> Vt[h][key]
        {
            half8 ra0, ra1, rb0, rb1;
            #pragma unroll
            for (int i = 0; i < 8; ++i) {
                U32H t; t.u = *(const unsigned int*)&Ks[(n0t + i) * KS_STR + h0];
                ra0[i] = t.h[0]; rb0[i] = t.h[1];
            }
            #pragma unroll
            for (int i = 8; i < 16; ++i) {
                U32H t; t.u = *(const unsigned int*)&Ks[(n0t + i) * KS_STR + h0];
                ra1[i - 8] = t.h[0]; rb1[i - 8] = t.h[1];
            }
            *(half8*)&Vt[(h0    ) * VT_STR + n0t    ] = ra0;
            *(half8*)&Vt[(h0    ) * VT_STR + n0t + 8] = ra1;
            *(half8*)&Vt[(h0 + 1) * VT_STR + n0t    ] = rb0;
            *(half8*)&Vt[(h0 + 1) * VT_STR + n0t + 8] = rb1;
        }
        __syncthreads();                 // Vt ready

        // ---- S^T = K . Q^T : tile nt -> keys nt*16+quad*4+r, col q=lc ----
        f32x4 S[4];
        #pragma unroll
        for (int nt = 0; nt < 4; ++nt) {
            f32x4 acc = zero4;
            #pragma unroll
            for (int s4 = 0; s4 < 4; ++s4) {
                half8 kf = *(half8*)&Ks[(nt * 16 + lc) * KS_STR + 32 * s4 + quad * 8];
                acc = __builtin_amdgcn_mfma_f32_16x16x32_f16(kf, qf[s4], acc, 0, 0, 0);
            }
            S[nt] = acc;
        }

        // ---- online softmax over keys (in-lane + 2 shuffles) ----
        float tmax = S[0][0];
        #pragma unroll
        for (int nt = 0; nt < 4; ++nt)
            #pragma unroll
            for (int r = 0; r < 4; ++r)
                tmax = fmaxf(tmax, S[nt][r]);
        tmax = fmaxf(tmax, __shfl_xor(tmax, 16, 64));
        tmax = fmaxf(tmax, __shfl_xor(tmax, 32, 64));

        const float nm = fmaxf(rmax, tmax);
        const float alpha = exp2f((rmax - nm) * L2E);
        rmax = nm;

        #pragma unroll
        for (int nt = 0; nt < 4; ++nt)
            #pragma unroll
            for (int r = 0; r < 4; ++r)
                S[nt][r] = exp2f((S[nt][r] - nm) * L2E);

        #pragma unroll
        for (int ct = 0; ct < 8; ++ct) O[ct] *= alpha;
        Osum *= alpha;

        // ---- O^T += V^T.P^T via 16x16x16 (B operand = S regs, no LDS) ----
        #pragma unroll
        for (int nt = 0; nt < 4; ++nt) {
            half4 pb;
            pb[0] = (_Float16)S[nt][0]; pb[1] = (_Float16)S[nt][1];
            pb[2] = (_Float16)S[nt][2]; pb[3] = (_Float16)S[nt][3];
            Osum = __builtin_amdgcn_mfma_f32_16x16x16f16(ones4, pb, Osum, 0, 0, 0);
            #pragma unroll
            for (int ct = 0; ct < 8; ++ct) {
                half4 af = *(half4*)&Vt[(ct * 16 + lc) * VT_STR + nt * 16 + quad * 4];
                O[ct] = __builtin_amdgcn_mfma_f32_16x16x16f16(af, pb, O[ct], 0, 0, 0);
            }
        }
    }

    if (splits == 1) {
        const float inv = 1.0f / Osum[0];
        float* orow = out + ((size_t)b * QQ + m0 + wave * 16 + lc) * HH;
        #pragma unroll
        for (int ct = 0; ct < 8; ++ct) {
            f32x4 v = O[ct] * inv;
            *(f32x4*)&orow[ct * 16 + quad * 4] = v;
        }
        return;
    }

    // ---- write partials ----
    const size_t mBase = (size_t)splits * OSPLIT;
    const size_t lBase = mBase + (size_t)splits * MLSPLIT;
    float* po = ws + ((size_t)s * NGROUPS + g) * (BM * HH) + (wave * 16 + lc) * HH;
    #pragma unroll
    for (int ct = 0; ct < 8; ++ct)
        *(f32x4*)&po[ct * 16 + quad * 4] = O[ct];
    if (quad == 0) {
        const size_t idx = (size_t)(s * NGROUPS + g) * BM + wave * 16 + lc;
        ws[mBase + idx] = rmax;
        ws[lBase + idx] = Osum[0];
    }

    // ---- last-arriver combine ----
    __threadfence();                     // release partials (device scope)
    if (tid == 0) {
        unsigned int* cnt = (unsigned int*)(ws + lBase + (size_t)splits * MLSPLIT);
        unsigned int old = atomicAdd(&cnt[g], 1u);
        lastFlag = (old == (unsigned int)(splits - 1));
    }
    __syncthreads();
    if (!lastFlag) return;
    __threadfence();                     // acquire others' partials

    const int h4 = (tid & 31) * 4;
    for (int q = tid >> 5; q < BM; q += 8) {
        float ms[4];
        float M = -3.0e38f;
        for (int sp = 0; sp < splits; ++sp) {
            ms[sp] = ws[mBase + (size_t)(sp * NGROUPS + g) * BM + q];
            M = fmaxf(M, ms[sp]);
        }
        float denom = 0.f;
        f32x4 val = {0.f, 0.f, 0.f, 0.f};
        for (int sp = 0; sp < splits; ++sp) {
            const float w = exp2f((ms[sp] - M) * L2E);
            denom += w * ws[lBase + (size_t)(sp * NGROUPS + g) * BM + q];
            const f32x4 ov = *(const f32x4*)&ws[(size_t)(sp * NGROUPS + g) * (BM * HH) + (size_t)q * HH + h4];
            val += w * ov;
        }
        const float inv = 1.0f / denom;
        *(f32x4*)&out[((size_t)b * QQ + m0 + q) * HH + h4] = val * inv;
    }
}

extern "C" void kernel_launch(void* const* d_in, const int* in_sizes, int n_in,
                              void* d_out, int out_size, void* d_ws, size_t ws_size,
                              hipStream_t stream) {
    const float* out_state = (const float*)d_in[0];
    const float* history   = (const float*)d_in[1];
    float* out = (float*)d_out;
    float* ws  = (float*)d_ws;

    int splits = 1;
    for (int cand = 4; cand >= 2; --cand) {
        const size_t bytes = (size_t)cand * (OSPLIT + 2 * MLSPLIT) * 4 + NGROUPS * 4;
        if (ws_size >= bytes) { splits = cand; break; }
    }

    if (splits > 1) {
        const size_t cntOff = (size_t)splits * (OSPLIT + 2 * MLSPLIT) * 4;
        hipMemsetAsync((char*)d_ws + cntOff, 0, NGROUPS * 4, stream);
    }
    attn_main<<<dim3(NGROUPS * splits), dim3(256), 0, stream>>>(out_state, history, out, ws, splits);
}

// Round 4
// 131.886 us; speedup vs baseline: 2.0332x; 2.0332x over previous
//
#include <hip/hip_runtime.h>
#include <math.h>

// Attn_83854941487646: out = softmax(tanh(Q) @ H^T) @ H
// B=8, Q=2048, K=2048, Hdim=128, fp32 in/out.
// R4: R2's proven 16x16x32 inner loop; 512-thread blocks (8 waves share one
//     Ks/Vt staging), LDS 51.2KB -> 3 blocks/CU (24 waves/CU), splits=6,
//     two-kernel combine (NO device fences), float4 combine.

typedef _Float16 half8 __attribute__((ext_vector_type(8)));
typedef _Float16 half4 __attribute__((ext_vector_type(4)));
typedef float    f32x4 __attribute__((ext_vector_type(4)));

#define QQ 2048
#define KK 2048
#define HH 128
#define BM 128               // q-rows per block (8 waves x 16)
#define BN 64
#define NTILES 32
#define NGROUPS 128          // 8 batches x 16 q-blocks of 128
#define KS_STR 132           // halves: 128 + 4 pad (2-way max, free)
#define VT_STR 68            // halves: 64 + 4 pad
#define PS_STR 66            // halves: 64 + 2 pad
#define L2E 1.44269504f
#define SPLITS_MAX 6
#define OSPLIT  ((size_t)NGROUPS * BM * HH)   // floats per split (O partials)
#define MLSPLIT ((size_t)NGROUPS * BM)        // floats per split (each of m,l)

union U32H { unsigned int u; _Float16 h[2]; };

__launch_bounds__(512, 6)
__global__ void attn_main(const float* __restrict__ out_state,
                          const float* __restrict__ history,
                          float* __restrict__ out,
                          float* __restrict__ ws,
                          int splits) {
    __shared__ _Float16 Ks[BN * KS_STR];      // 16896 B  [key][h]
    __shared__ _Float16 Vt[HH * VT_STR];      // 17408 B  [h][key]
    __shared__ _Float16 Ps[8][16 * PS_STR];   // 16896 B  per-wave P

    const int tid  = threadIdx.x;
    const int wave = tid >> 6;          // 0..7
    const int lane = tid & 63;
    const int quad = lane >> 4;
    const int lc   = lane & 15;

    const int bid = blockIdx.x;
    const int s   = bid / NGROUPS;      // split id
    const int g   = bid % NGROUPS;      // group id
    const int b   = g >> 4;
    const int qb  = g & 15;
    const int m0  = qb * BM;

    const int kt0 = (NTILES * s) / splits;
    const int kt1 = (NTILES * (s + 1)) / splits;

    // Q fragment (MFMA B operand for S^T = K.Q^T): lane holds Q[m=lc][k=quad*8+j]
    half8 qf[4];
    {
        const int m = m0 + wave * 16 + lc;
        const float* qrow = out_state + ((size_t)b * QQ + m) * HH;
        #pragma unroll
        for (int s4 = 0; s4 < 4; ++s4) {
            const int h0 = 32 * s4 + quad * 8;
            const float4 a = *(const float4*)(qrow + h0);
            const float4 c = *(const float4*)(qrow + h0 + 4);
            qf[s4][0] = (_Float16)tanhf(a.x); qf[s4][1] = (_Float16)tanhf(a.y);
            qf[s4][2] = (_Float16)tanhf(a.z); qf[s4][3] = (_Float16)tanhf(a.w);
            qf[s4][4] = (_Float16)tanhf(c.x); qf[s4][5] = (_Float16)tanhf(c.y);
            qf[s4][6] = (_Float16)tanhf(c.z); qf[s4][7] = (_Float16)tanhf(c.w);
        }
    }

    const f32x4 zero4 = {0.f, 0.f, 0.f, 0.f};
    f32x4 O[8];                 // O^T tile ct: rows h=16ct+quad*4+r, col q=lc
    #pragma unroll
    for (int i = 0; i < 8; ++i) O[i] = zero4;
    f32x4 Osum = zero4;
    float rmax = -3.0e38f;

    // staging maps (512 threads)
    const int r0  = tid >> 5;           // stage0/1: key row 0..15 (+16j)
    const int c4  = (tid & 31) * 4;     // stage0/1: h col (float4 / half4)
    const int h0  = 2 * (tid & 63);     // stage2: h-pair
    const int n0t = (tid >> 6) * 8;     // stage2: 8-key group per thread

    const half8 ones = {(_Float16)1.f,(_Float16)1.f,(_Float16)1.f,(_Float16)1.f,
                        (_Float16)1.f,(_Float16)1.f,(_Float16)1.f,(_Float16)1.f};

    for (int kt = kt0; kt < kt1; ++kt) {
        const int n0 = kt * BN;

        // stage 0: coalesced global prefetch (4 rows x f32x4 per thread)
        float4 gbuf[4];
        const float* hb = history + ((size_t)b * KK + n0) * HH;
        #pragma unroll
        for (int j = 0; j < 4; ++j)
            gbuf[j] = *(const float4*)(hb + (size_t)(r0 + 16 * j) * HH + c4);

        __syncthreads();                 // previous tile's compute done
        // stage 1: Ks row-major f16
        #pragma unroll
        for (int j = 0; j < 4; ++j) {
            half4 hv;
            hv[0] = (_Float16)gbuf[j].x; hv[1] = (_Float16)gbuf[j].y;
            hv[2] = (_Float16)gbuf[j].z; hv[3] = (_Float16)gbuf[j].w;
            *(half4*)&Ks[(r0 + 16 * j) * KS_STR + c4] = hv;
        }
        __syncthreads();                 // Ks ready
        // stage 2: transpose Ks -> Vt[h][key] (b32-pair reads, b128 writes)
        {
            half8 ra, rb;
            #pragma unroll
            for (int i = 0; i < 8; ++i) {
                U32H t; t.u = *(const unsigned int*)&Ks[(n0t + i) * KS_STR + h0];
                ra[i] = t.h[0]; rb[i] = t.h[1];
            }
            *(half8*)&Vt[(h0    ) * VT_STR + n0t] = ra;
            *(half8*)&Vt[(h0 + 1) * VT_STR + n0t] = rb;
        }
        __syncthreads();                 // Vt ready

        // ---- S^T = K . Q^T : tile nt -> keys nt*16+quad*4+r, col q=lc ----
        f32x4 S[4];
        #pragma unroll
        for (int nt = 0; nt < 4; ++nt) {
            f32x4 acc = zero4;
            #pragma unroll
            for (int s4 = 0; s4 < 4; ++s4) {
                half8 kf = *(half8*)&Ks[(nt * 16 + lc) * KS_STR + 32 * s4 + quad * 8];
                acc = __builtin_amdgcn_mfma_f32_16x16x32_f16(kf, qf[s4], acc, 0, 0, 0);
            }
            S[nt] = acc;
        }

        // ---- online softmax over keys (in-lane + 2 shuffles) ----
        float tmax = S[0][0];
        #pragma unroll
        for (int nt = 0; nt < 4; ++nt)
            #pragma unroll
            for (int r = 0; r < 4; ++r)
                tmax = fmaxf(tmax, S[nt][r]);
        tmax = fmaxf(tmax, __shfl_xor(tmax, 16, 64));
        tmax = fmaxf(tmax, __shfl_xor(tmax, 32, 64));

        const float nm = fmaxf(rmax, tmax);
        const float alpha = exp2f((rmax - nm) * L2E);
        rmax = nm;

        #pragma unroll
        for (int nt = 0; nt < 4; ++nt)
            #pragma unroll
            for (int r = 0; r < 4; ++r)
                S[nt][r] = exp2f((S[nt][r] - nm) * L2E);

        #pragma unroll
        for (int ct = 0; ct < 8; ++ct) O[ct] *= alpha;
        Osum *= alpha;

        // ---- P^T -> per-wave LDS Ps[q][key] ----
        #pragma unroll
        for (int nt = 0; nt < 4; ++nt) {
            half4 pv;
            pv[0] = (_Float16)S[nt][0]; pv[1] = (_Float16)S[nt][1];
            pv[2] = (_Float16)S[nt][2]; pv[3] = (_Float16)S[nt][3];
            *(half4*)&Ps[wave][lc * PS_STR + nt * 16 + quad * 4] = pv;
        }

        // ---- O^T += V^T.P^T ; rowsum via ones-MFMA ----
        #pragma unroll
        for (int s2 = 0; s2 < 2; ++s2) {
            half8 pb = *(half8*)&Ps[wave][lc * PS_STR + s2 * 32 + quad * 8];
            Osum = __builtin_amdgcn_mfma_f32_16x16x32_f16(ones, pb, Osum, 0, 0, 0);
            #pragma unroll
            for (int ct = 0; ct < 8; ++ct) {
                half8 vf = *(half8*)&Vt[(ct * 16 + lc) * VT_STR + s2 * 32 + quad * 8];
                O[ct] = __builtin_amdgcn_mfma_f32_16x16x32_f16(vf, pb, O[ct], 0, 0, 0);
            }
        }
    }

    if (splits == 1) {
        const float inv = 1.0f / Osum[0];
        float* orow = out + ((size_t)b * QQ + m0 + wave * 16 + lc) * HH;
        #pragma unroll
        for (int ct = 0; ct < 8; ++ct) {
            f32x4 v = O[ct] * inv;
            *(f32x4*)&orow[ct * 16 + quad * 4] = v;
        }
        return;
    }

    // ---- write partials (no fences; kernel boundary is the release) ----
    const size_t mBase = (size_t)splits * OSPLIT;
    const size_t lBase = mBase + (size_t)splits * MLSPLIT;
    float* po = ws + ((size_t)s * NGROUPS + g) * ((size_t)BM * HH) + (size_t)(wave * 16 + lc) * HH;
    #pragma unroll
    for (int ct = 0; ct < 8; ++ct)
        *(f32x4*)&po[ct * 16 + quad * 4] = O[ct];
    if (quad == 0) {
        const size_t idx = (size_t)(s * NGROUPS + g) * BM + wave * 16 + lc;
        ws[mBase + idx] = rmax;
        ws[lBase + idx] = Osum[0];
    }
}

__global__ void attn_combine(const float* __restrict__ ws,
                             float* __restrict__ out,
                             int splits) {
    const int idx = blockIdx.x * 256 + threadIdx.x;   // over B*QQ*HH/4 = 2^19
    const int h4   = (idx & 31) * 4;
    const int rest = idx >> 5;
    const int q    = rest & 2047;
    const int b    = rest >> 11;
    const int g    = b * 16 + (q >> 7);
    const int qr   = q & 127;

    const size_t mBase = (size_t)splits * OSPLIT;
    const size_t lBase = mBase + (size_t)splits * MLSPLIT;

    float ms[SPLITS_MAX];
    float M = -3.0e38f;
    for (int sp = 0; sp < splits; ++sp) {
        ms[sp] = ws[mBase + (size_t)(sp * NGROUPS + g) * BM + qr];
        M = fmaxf(M, ms[sp]);
    }
    float denom = 0.f;
    f32x4 val = {0.f, 0.f, 0.f, 0.f};
    for (int sp = 0; sp < splits; ++sp) {
        const float w = exp2f((ms[sp] - M) * L2E);
        denom += w * ws[lBase + (size_t)(sp * NGROUPS + g) * BM + qr];
        const f32x4 ov = *(const f32x4*)&ws[(size_t)(sp * NGROUPS + g) * ((size_t)BM * HH)
                                            + (size_t)qr * HH + h4];
        val += w * ov;
    }
    const float inv = 1.0f / denom;
    *(f32x4*)&out[((size_t)b * QQ + q) * HH + h4] = val * inv;
}

extern "C" void kernel_launch(void* const* d_in, const int* in_sizes, int n_in,
                              void* d_out, int out_size, void* d_ws, size_t ws_size,
                              hipStream_t stream) {
    const float* out_state = (const float*)d_in[0];
    const float* history   = (const float*)d_in[1];
    float* out = (float*)d_out;
    float* ws  = (float*)d_ws;

    int splits = 1;
    for (int cand = SPLITS_MAX; cand >= 2; --cand) {
        const size_t bytes = (size_t)cand * (OSPLIT + 2 * MLSPLIT) * 4;
        if (ws_size >= bytes) { splits = cand; break; }
    }

    attn_main<<<dim3(NGROUPS * splits), dim3(512), 0, stream>>>(out_state, history, out, ws, splits);
    if (splits > 1)
        attn_combine<<<dim3((8 * QQ * HH / 4) / 256), dim3(256), 0, stream>>>(ws, out, splits);
}

// Round 5
// 118.722 us; speedup vs baseline: 2.2586x; 1.1109x over previous
//
#include <hip/hip_runtime.h>
#include <math.h>

// Attn_83854941487646: out = softmax(tanh(Q) @ H^T) @ H
// B=8, Q=2048, K=2048, Hdim=128, fp32 in/out.
// R5: XCD swizzle (batch == XCD -> history L2-resident, kills 93MB re-fetch)
//     + dual q-strip per wave (each kf/vf LDS read feeds 2 MFMAs)
//     + splits=6 flash split-K, 2-kernel combine (no fences).

typedef _Float16 half8 __attribute__((ext_vector_type(8)));
typedef _Float16 half4 __attribute__((ext_vector_type(4)));
typedef float    f32x4 __attribute__((ext_vector_type(4)));

#define QQ 2048
#define KK 2048
#define HH 128
#define BM 128               // q-rows per block (4 waves x 32)
#define BN 64
#define NTILES 32
#define NGROUPS 128          // 8 batches x 16 q-blocks
#define KS_STR 132           // halves: 128 + 4 pad
#define VT_STR 68            // halves: 64 + 4 pad
#define PS_STR 66            // halves: 64 + 2 pad
#define L2E 1.44269504f
#define SPLITS_MAX 6
#define OSPLIT  ((size_t)NGROUPS * BM * HH)   // floats per split (O partials)
#define MLSPLIT ((size_t)NGROUPS * BM)        // floats per split (each of m,l)

union U32H { unsigned int u; _Float16 h[2]; };

__launch_bounds__(256, 3)
__global__ void attn_main(const float* __restrict__ out_state,
                          const float* __restrict__ history,
                          float* __restrict__ out,
                          float* __restrict__ ws,
                          int splits) {
    __shared__ _Float16 Ks[BN * KS_STR];         // 16896 B  [key][h]
    __shared__ _Float16 Vt[HH * VT_STR];         // 17408 B  [h][key]
    __shared__ _Float16 Ps[4][2][16 * PS_STR];   // 16896 B  per-wave, per-strip P

    const int tid  = threadIdx.x;
    const int wave = tid >> 6;          // 0..3
    const int lane = tid & 63;
    const int quad = lane >> 4;
    const int lc   = lane & 15;

    // XCD swizzle: dispatch is round-robin over 8 XCDs -> batch b pinned to XCD b,
    // so each XCD's 4MB L2 caches its batch's 1MB history slice.
    const int bid = blockIdx.x;
    const int b   = bid & 7;
    const int t   = bid >> 3;
    const int qb  = t & 15;
    const int s   = t >> 4;             // split id
    const int g   = b * 16 + qb;        // group id (combine-kernel compatible)
    const int m0  = qb * BM;

    const int kt0 = (NTILES * s) / splits;
    const int kt1 = (NTILES * (s + 1)) / splits;

    // Q fragments for two strips: strip A = q rows m0+wave*32+lc, strip B = +16.
    half8 qfa[4], qfb[4];
    {
        const float* qrowA = out_state + ((size_t)b * QQ + m0 + wave * 32 + lc) * HH;
        const float* qrowB = qrowA + 16 * HH;
        #pragma unroll
        for (int s4 = 0; s4 < 4; ++s4) {
            const int h0 = 32 * s4 + quad * 8;
            float4 a = *(const float4*)(qrowA + h0);
            float4 c = *(const float4*)(qrowA + h0 + 4);
            qfa[s4][0] = (_Float16)tanhf(a.x); qfa[s4][1] = (_Float16)tanhf(a.y);
            qfa[s4][2] = (_Float16)tanhf(a.z); qfa[s4][3] = (_Float16)tanhf(a.w);
            qfa[s4][4] = (_Float16)tanhf(c.x); qfa[s4][5] = (_Float16)tanhf(c.y);
            qfa[s4][6] = (_Float16)tanhf(c.z); qfa[s4][7] = (_Float16)tanhf(c.w);
            a = *(const float4*)(qrowB + h0);
            c = *(const float4*)(qrowB + h0 + 4);
            qfb[s4][0] = (_Float16)tanhf(a.x); qfb[s4][1] = (_Float16)tanhf(a.y);
            qfb[s4][2] = (_Float16)tanhf(a.z); qfb[s4][3] = (_Float16)tanhf(a.w);
            qfb[s4][4] = (_Float16)tanhf(c.x); qfb[s4][5] = (_Float16)tanhf(c.y);
            qfb[s4][6] = (_Float16)tanhf(c.z); qfb[s4][7] = (_Float16)tanhf(c.w);
        }
    }

    const f32x4 zero4 = {0.f, 0.f, 0.f, 0.f};
    f32x4 Oa[8], Ob[8];
    #pragma unroll
    for (int i = 0; i < 8; ++i) { Oa[i] = zero4; Ob[i] = zero4; }
    f32x4 OsumA = zero4, OsumB = zero4;
    float rmaxA = -3.0e38f, rmaxB = -3.0e38f;

    // staging maps (256 threads)
    const int r0  = tid >> 5;           // stage0/1: key row 0..7 (+8j)
    const int c4  = (tid & 31) * 4;     // stage0/1: h col
    const int h0  = 2 * (tid & 63);     // stage2: h-pair
    const int n0t = (tid >> 6) * 16;    // stage2: 16-key group

    const half8 ones = {(_Float16)1.f,(_Float16)1.f,(_Float16)1.f,(_Float16)1.f,
                        (_Float16)1.f,(_Float16)1.f,(_Float16)1.f,(_Float16)1.f};

    for (int kt = kt0; kt < kt1; ++kt) {
        const int n0 = kt * BN;

        // stage 0: coalesced global prefetch (8 rows x f32x4 per thread)
        float4 gbuf[8];
        const float* hb = history + ((size_t)b * KK + n0) * HH;
        #pragma unroll
        for (int j = 0; j < 8; ++j)
            gbuf[j] = *(const float4*)(hb + (size_t)(r0 + 8 * j) * HH + c4);

        __syncthreads();                 // previous tile's compute done
        #pragma unroll
        for (int j = 0; j < 8; ++j) {
            half4 hv;
            hv[0] = (_Float16)gbuf[j].x; hv[1] = (_Float16)gbuf[j].y;
            hv[2] = (_Float16)gbuf[j].z; hv[3] = (_Float16)gbuf[j].w;
            *(half4*)&Ks[(r0 + 8 * j) * KS_STR + c4] = hv;
        }
        __syncthreads();                 // Ks ready
        // stage 2: transpose Ks -> Vt[h][key]
        {
            half8 ra0, ra1, rb0, rb1;
            #pragma unroll
            for (int i = 0; i < 8; ++i) {
                U32H t2; t2.u = *(const unsigned int*)&Ks[(n0t + i) * KS_STR + h0];
                ra0[i] = t2.h[0]; rb0[i] = t2.h[1];
            }
            #pragma unroll
            for (int i = 8; i < 16; ++i) {
                U32H t2; t2.u = *(const unsigned int*)&Ks[(n0t + i) * KS_STR + h0];
                ra1[i - 8] = t2.h[0]; rb1[i - 8] = t2.h[1];
            }
            *(half8*)&Vt[(h0    ) * VT_STR + n0t    ] = ra0;
            *(half8*)&Vt[(h0    ) * VT_STR + n0t + 8] = ra1;
            *(half8*)&Vt[(h0 + 1) * VT_STR + n0t    ] = rb0;
            *(half8*)&Vt[(h0 + 1) * VT_STR + n0t + 8] = rb1;
        }
        __syncthreads();                 // Vt ready

        // ---- S^T = K.Q^T for both strips: each kf read feeds 2 MFMAs ----
        f32x4 Sa[4], Sb[4];
        #pragma unroll
        for (int nt = 0; nt < 4; ++nt) {
            f32x4 aa = zero4, ab = zero4;
            #pragma unroll
            for (int s4 = 0; s4 < 4; ++s4) {
                half8 kf = *(half8*)&Ks[(nt * 16 + lc) * KS_STR + 32 * s4 + quad * 8];
                aa = __builtin_amdgcn_mfma_f32_16x16x32_f16(kf, qfa[s4], aa, 0, 0, 0);
                ab = __builtin_amdgcn_mfma_f32_16x16x32_f16(kf, qfb[s4], ab, 0, 0, 0);
            }
            Sa[nt] = aa; Sb[nt] = ab;
        }

        // ---- online softmax (both strips, independent per-lane) ----
        float tmaxA = Sa[0][0], tmaxB = Sb[0][0];
        #pragma unroll
        for (int nt = 0; nt < 4; ++nt)
            #pragma unroll
            for (int r = 0; r < 4; ++r) {
                tmaxA = fmaxf(tmaxA, Sa[nt][r]);
                tmaxB = fmaxf(tmaxB, Sb[nt][r]);
            }
        tmaxA = fmaxf(tmaxA, __shfl_xor(tmaxA, 16, 64));
        tmaxA = fmaxf(tmaxA, __shfl_xor(tmaxA, 32, 64));
        tmaxB = fmaxf(tmaxB, __shfl_xor(tmaxB, 16, 64));
        tmaxB = fmaxf(tmaxB, __shfl_xor(tmaxB, 32, 64));

        const float nmA = fmaxf(rmaxA, tmaxA);
        const float nmB = fmaxf(rmaxB, tmaxB);
        const float alphaA = exp2f((rmaxA - nmA) * L2E);
        const float alphaB = exp2f((rmaxB - nmB) * L2E);
        rmaxA = nmA; rmaxB = nmB;

        #pragma unroll
        for (int nt = 0; nt < 4; ++nt)
            #pragma unroll
            for (int r = 0; r < 4; ++r) {
                Sa[nt][r] = exp2f((Sa[nt][r] - nmA) * L2E);
                Sb[nt][r] = exp2f((Sb[nt][r] - nmB) * L2E);
            }

        #pragma unroll
        for (int ct = 0; ct < 8; ++ct) { Oa[ct] *= alphaA; Ob[ct] *= alphaB; }
        OsumA *= alphaA; OsumB *= alphaB;

        // ---- P^T -> per-wave per-strip LDS ----
        #pragma unroll
        for (int nt = 0; nt < 4; ++nt) {
            half4 pva, pvb;
            pva[0] = (_Float16)Sa[nt][0]; pva[1] = (_Float16)Sa[nt][1];
            pva[2] = (_Float16)Sa[nt][2]; pva[3] = (_Float16)Sa[nt][3];
            pvb[0] = (_Float16)Sb[nt][0]; pvb[1] = (_Float16)Sb[nt][1];
            pvb[2] = (_Float16)Sb[nt][2]; pvb[3] = (_Float16)Sb[nt][3];
            *(half4*)&Ps[wave][0][lc * PS_STR + nt * 16 + quad * 4] = pva;
            *(half4*)&Ps[wave][1][lc * PS_STR + nt * 16 + quad * 4] = pvb;
        }

        // ---- O^T += V^T.P^T (vf read shared by both strips); ones-MFMA rowsum ----
        #pragma unroll
        for (int s2 = 0; s2 < 2; ++s2) {
            half8 pba = *(half8*)&Ps[wave][0][lc * PS_STR + s2 * 32 + quad * 8];
            half8 pbb = *(half8*)&Ps[wave][1][lc * PS_STR + s2 * 32 + quad * 8];
            OsumA = __builtin_amdgcn_mfma_f32_16x16x32_f16(ones, pba, OsumA, 0, 0, 0);
            OsumB = __builtin_amdgcn_mfma_f32_16x16x32_f16(ones, pbb, OsumB, 0, 0, 0);
            #pragma unroll
            for (int ct = 0; ct < 8; ++ct) {
                half8 vf = *(half8*)&Vt[(ct * 16 + lc) * VT_STR + s2 * 32 + quad * 8];
                Oa[ct] = __builtin_amdgcn_mfma_f32_16x16x32_f16(vf, pba, Oa[ct], 0, 0, 0);
                Ob[ct] = __builtin_amdgcn_mfma_f32_16x16x32_f16(vf, pbb, Ob[ct], 0, 0, 0);
            }
        }
    }

    const int qA = wave * 32 + lc;        // strip A local q-row
    if (splits == 1) {
        const float invA = 1.0f / OsumA[0];
        const float invB = 1.0f / OsumB[0];
        float* orowA = out + ((size_t)b * QQ + m0 + qA) * HH;
        float* orowB = orowA + 16 * HH;
        #pragma unroll
        for (int ct = 0; ct < 8; ++ct) {
            f32x4 va = Oa[ct] * invA;
            f32x4 vb = Ob[ct] * invB;
            *(f32x4*)&orowA[ct * 16 + quad * 4] = va;
            *(f32x4*)&orowB[ct * 16 + quad * 4] = vb;
        }
        return;
    }

    // ---- write partials (kernel boundary is the release fence) ----
    const size_t mBase = (size_t)splits * OSPLIT;
    const size_t lBase = mBase + (size_t)splits * MLSPLIT;
    float* poA = ws + ((size_t)s * NGROUPS + g) * ((size_t)BM * HH) + (size_t)qA * HH;
    float* poB = poA + 16 * HH;
    #pragma unroll
    for (int ct = 0; ct < 8; ++ct) {
        *(f32x4*)&poA[ct * 16 + quad * 4] = Oa[ct];
        *(f32x4*)&poB[ct * 16 + quad * 4] = Ob[ct];
    }
    if (quad == 0) {
        const size_t idx = (size_t)(s * NGROUPS + g) * BM + qA;
        ws[mBase + idx]      = rmaxA;
        ws[lBase + idx]      = OsumA[0];
        ws[mBase + idx + 16] = rmaxB;
        ws[lBase + idx + 16] = OsumB[0];
    }
}

__global__ void attn_combine(const float* __restrict__ ws,
                             float* __restrict__ out,
                             int splits) {
    const int idx = blockIdx.x * 256 + threadIdx.x;   // over B*QQ*HH/4 = 2^19
    const int h4   = (idx & 31) * 4;
    const int rest = idx >> 5;
    const int q    = rest & 2047;
    const int b    = rest >> 11;
    const int g    = b * 16 + (q >> 7);
    const int qr   = q & 127;

    const size_t mBase = (size_t)splits * OSPLIT;
    const size_t lBase = mBase + (size_t)splits * MLSPLIT;

    float ms[SPLITS_MAX];
    float M = -3.0e38f;
    for (int sp = 0; sp < splits; ++sp) {
        ms[sp] = ws[mBase + (size_t)(sp * NGROUPS + g) * BM + qr];
        M = fmaxf(M, ms[sp]);
    }
    float denom = 0.f;
    f32x4 val = {0.f, 0.f, 0.f, 0.f};
    for (int sp = 0; sp < splits; ++sp) {
        const float w = exp2f((ms[sp] - M) * L2E);
        denom += w * ws[lBase + (size_t)(sp * NGROUPS + g) * BM + qr];
        const f32x4 ov = *(const f32x4*)&ws[(size_t)(sp * NGROUPS + g) * ((size_t)BM * HH)
                                            + (size_t)qr * HH + h4];
        val += w * ov;
    }
    const float inv = 1.0f / denom;
    *(f32x4*)&out[((size_t)b * QQ + q) * HH + h4] = val * inv;
}

extern "C" void kernel_launch(void* const* d_in, const int* in_sizes, int n_in,
                              void* d_out, int out_size, void* d_ws, size_t ws_size,
                              hipStream_t stream) {
    const float* out_state = (const float*)d_in[0];
    const float* history   = (const float*)d_in[1];
    float* out = (float*)d_out;
    float* ws  = (float*)d_ws;

    int splits = 1;
    for (int cand = SPLITS_MAX; cand >= 2; --cand) {
        const size_t bytes = (size_t)cand * (OSPLIT + 2 * MLSPLIT) * 4;
        if (ws_size >= bytes) { splits = cand; break; }
    }

    attn_main<<<dim3(NGROUPS * splits), dim3(256), 0, stream>>>(out_state, history, out, ws, splits);
    if (splits > 1)
        attn_combine<<<dim3((8 * QQ * HH / 4) / 256), dim3(256), 0, stream>>>(ws, out, splits);
}